// Round 4
// baseline (1458.371 us; speedup 1.0000x reference)
//
#include <hip/hip_runtime.h>
#include <hip/hip_bf16.h>

// ---------------- constants (Swin block geometry) ----------------
#define C_DIM   384
#define HEADS   12
#define HDIM    32
#define NTOK    49
#define TOT_WIN 2048        // 32 images * 64 windows
#define M_TOK   100352      // TOT_WIN*49
#define QKV_N   1152
#define MLP_N   1536
#define SHIFT_V 3

typedef __bf16 bf16x8_t __attribute__((ext_vector_type(8)));
typedef float  f32x4_t  __attribute__((ext_vector_type(4)));

__device__ inline float b2f(ushort u) {
    union { unsigned u; float f; } p; p.u = ((unsigned)u) << 16; return p.f;
}
__device__ inline ushort f2b(float f) {
    union { float f; unsigned u; } p; p.f = f;
    unsigned r = p.u + 0x7FFF + ((p.u >> 16) & 1);
    return (ushort)(r >> 16);
}
// dtype-branched scalar load from a native input buffer
__device__ inline float ldin(const void* p, size_t i, int dt) {
    return dt ? b2f(((const ushort*)p)[i]) : ((const float*)p)[i];
}

// windowed-token index (global) -> original token row (shift roll, +3 mod 56)
__device__ inline int win2tok(int grow) {
    int widx = grow / 49, tok = grow - widx * 49;
    int b = widx >> 6, w_ = widx & 63;
    int wh = w_ >> 3, ww = w_ & 7;
    int r = tok / 7, c = tok - r * 7;
    int h = wh * 7 + r + SHIFT_V; if (h >= 56) h -= 56;
    int wc = ww * 7 + c + SHIFT_V; if (wc >= 56) wc -= 56;
    return b * 3136 + h * 56 + wc;
}

// ---------------- dtype sniffer: even-index ushorts sane-bf16 test ----------------
__global__ void sniff_kernel(const ushort* x16, int* flag) {
    const int tid = threadIdx.x;
    int cnt = 0;
    for (int i = tid; i < 4096; i += 256) {
        ushort u = x16[2 * i];
        int e = (u >> 7) & 0xFF;
        if ((u & 0x7FFF) == 0 || (e >= 107 && e <= 147)) cnt++;
    }
    __shared__ int ss[256];
    ss[tid] = cnt; __syncthreads();
    for (int s = 128; s; s >>= 1) { if (tid < s) ss[tid] += ss[tid + s]; __syncthreads(); }
    if (tid == 0) *flag = (ss[0] >= 2048) ? 1 : 0;   // 1 = bf16 storage, 0 = f32 storage
}

// ---------------- weight convert: native -> canonical bf16 ----------------
__global__ void cvt_w_kernel(const void* src, ushort* dst, int n, const int* flagp) {
    const int dt = *flagp;
    for (int i = blockIdx.x * blockDim.x + threadIdx.x; i < n; i += gridDim.x * blockDim.x)
        dst[i] = dt ? ((const ushort*)src)[i] : f2b(((const float*)src)[i]);
}

// ---------------- small params -> canonical f32 (concatenated) ----------------
// layout (floats): n1g 0 | n1b 384 | qkv_b 768 | proj_b 1920 | n2g 2304 |
//                  n2b 2688 | fc1_b 3072 | fc2_b 4608 | rpb 4992..7020
__global__ void cvt_p_kernel(const void* n1g, const void* n1b, const void* qkvb,
                             const void* projb, const void* n2g, const void* n2b,
                             const void* fc1b, const void* fc2b, const void* rpb,
                             float* prm, const int* flagp) {
    const int dt = *flagp;
    for (int i = threadIdx.x; i < 7020; i += 256) {
        float v;
        if      (i < 384)  v = ldin(n1g,  i,        dt);
        else if (i < 768)  v = ldin(n1b,  i - 384,  dt);
        else if (i < 1920) v = ldin(qkvb, i - 768,  dt);
        else if (i < 2304) v = ldin(projb,i - 1920, dt);
        else if (i < 2688) v = ldin(n2g,  i - 2304, dt);
        else if (i < 3072) v = ldin(n2b,  i - 2688, dt);
        else if (i < 4608) v = ldin(fc1b, i - 3072, dt);
        else if (i < 4992) v = ldin(fc2b, i - 4608, dt);
        else               v = ldin(rpb,  i - 4992, dt);
        prm[i] = v;
    }
}

// ---------------- LayerNorm (MODE 0: gather shift+window-partition from x;
//                  MODE 1: plain rows moff+m from d_out) -> bf16 out ----------------
template<int MODE>
__global__ __launch_bounds__(256) void ln_kernel(
    const void* __restrict__ x, const float* __restrict__ g,
    const float* __restrict__ b, ushort* __restrict__ out,
    const int* flagp, int moff)
{
    const int dt = *flagp;
    const int wid = threadIdx.x >> 6, lane = threadIdx.x & 63;
    const int m = blockIdx.x * 4 + wid;               // chunk-local token index
    const int src = (MODE == 0) ? win2tok(moff + m) : (moff + m);

    float v[6]; float s = 0.f, sq = 0.f;
    #pragma unroll
    for (int k = 0; k < 6; ++k) {
        v[k] = ldin(x, (size_t)src * C_DIM + lane + 64 * k, dt);
        s += v[k]; sq += v[k] * v[k];
    }
    #pragma unroll
    for (int off = 32; off; off >>= 1) {
        s  += __shfl_xor(s,  off, 64);
        sq += __shfl_xor(sq, off, 64);
    }
    float mean = s * (1.f / 384.f);
    float var  = sq * (1.f / 384.f) - mean * mean;
    float rstd = rsqrtf(var + 1e-5f);
    #pragma unroll
    for (int k = 0; k < 6; ++k) {
        int col = lane + 64 * k;
        out[(size_t)m * C_DIM + col] =
            f2b((v[k] - mean) * rstd * g[col] + b[col]);
    }
}

// ---------------- GEMM: C[m][n] = sum_k A[m][k]*W[n][k] (+bias; epilogue per MODE) -------
// MODE 0: QKV  -> outb bf16 chunk-local, N=1152
// MODE 1: PROJ -> outv row win2tok(moff+grow), + resid, N=384 (dtype-branched)
// MODE 2: FC1  -> GELU(exact erf) -> outb bf16 chunk-local, N=1536
// MODE 3: FC2  -> outv row moff+grow, + resid (same buffer ok), N=384 (dtype-branched)
template<int MODE>
__global__ __launch_bounds__(256, 2) void gemm_bt(
    const ushort* __restrict__ A, const ushort* __restrict__ W,
    const float* __restrict__ bias, ushort* outb, void* outv,
    const void* resid, const int* flagp, int N, int K, int Mrows, int moff)
{
    __shared__ __align__(16) ushort As[128 * 32];
    __shared__ __align__(16) ushort Bs[128 * 32];

    const int dt   = *flagp;
    const int tid  = threadIdx.x;
    const int wid  = tid >> 6;
    const int lane = tid & 63;
    const int bm = blockIdx.x * 128;
    const int bn = blockIdx.y * 128;
    const int wm = (wid >> 1) * 64;
    const int wn = (wid & 1) * 64;
    const int lrow = lane & 15;
    const int lk   = (lane >> 4) << 3;

    const int c0    = wid * 2;
    const int srow0 = c0 * 16 + (lane >> 2);          // 0..127 across block
    const int srow1 = srow0 + 16;
    const int skoff = (lane & 3) << 3;                // 0,8,16,24 ushorts

    const int ar0 = (bm + srow0 < Mrows) ? (bm + srow0) : (Mrows - 1);
    const int ar1 = (bm + srow1 < Mrows) ? (bm + srow1) : (Mrows - 1);

    f32x4_t acc[4][4];
    #pragma unroll
    for (int m = 0; m < 4; ++m)
        #pragma unroll
        for (int n = 0; n < 4; ++n) acc[m][n] = (f32x4_t){0.f, 0.f, 0.f, 0.f};

    const int nk = K >> 5;
    for (int kt = 0; kt < nk; ++kt) {
        const int k0 = kt << 5;
        bf16x8_t va0 = *(const bf16x8_t*)(A + (size_t)ar0 * K + k0 + skoff);
        bf16x8_t va1 = *(const bf16x8_t*)(A + (size_t)ar1 * K + k0 + skoff);
        bf16x8_t vb0 = *(const bf16x8_t*)(W + (size_t)(bn + srow0) * K + k0 + skoff);
        bf16x8_t vb1 = *(const bf16x8_t*)(W + (size_t)(bn + srow1) * K + k0 + skoff);
        __syncthreads();                               // prior LDS reads done
        *(bf16x8_t*)&As[srow0 * 32 + skoff] = va0;
        *(bf16x8_t*)&As[srow1 * 32 + skoff] = va1;
        *(bf16x8_t*)&Bs[srow0 * 32 + skoff] = vb0;
        *(bf16x8_t*)&Bs[srow1 * 32 + skoff] = vb1;
        __syncthreads();                               // stores visible
        bf16x8_t af[4], bfr[4];
        #pragma unroll
        for (int m = 0; m < 4; ++m)
            af[m] = *(const bf16x8_t*)&As[(wm + m * 16 + lrow) * 32 + lk];
        #pragma unroll
        for (int n = 0; n < 4; ++n)
            bfr[n] = *(const bf16x8_t*)&Bs[(wn + n * 16 + lrow) * 32 + lk];
        #pragma unroll
        for (int m = 0; m < 4; ++m)
            #pragma unroll
            for (int n = 0; n < 4; ++n)
                acc[m][n] = __builtin_amdgcn_mfma_f32_16x16x32_bf16(
                    af[m], bfr[n], acc[m][n], 0, 0, 0);
    }

    // epilogue: D col = lane&15, row = (lane>>4)*4 + reg  [m89-verified layout]
    float biasf[4]; int coln[4];
    #pragma unroll
    for (int n = 0; n < 4; ++n) {
        coln[n] = bn + wn + n * 16 + lrow;
        biasf[n] = bias[coln[n]];
    }
    const int rbase = bm + wm + ((lane >> 4) << 2);
    #pragma unroll
    for (int m = 0; m < 4; ++m) {
        #pragma unroll
        for (int j = 0; j < 4; ++j) {
            int grow = rbase + m * 16 + j;
            if (grow >= Mrows) continue;
            #pragma unroll
            for (int n = 0; n < 4; ++n) {
                float v = acc[m][n][j] + biasf[n];
                if (MODE == 0) {
                    outb[(size_t)grow * N + coln[n]] = f2b(v);
                } else if (MODE == 2) {
                    v = 0.5f * v * (1.0f + erff(v * 0.70710678118654752f));
                    outb[(size_t)grow * N + coln[n]] = f2b(v);
                } else {
                    size_t orow = (MODE == 1) ? (size_t)win2tok(moff + grow)
                                              : (size_t)(moff + grow);
                    size_t oidx = orow * (size_t)N + coln[n];
                    float r = v + ldin(resid, oidx, dt);
                    if (dt) ((ushort*)outv)[oidx] = f2b(r);
                    else    ((float*) outv)[oidx] = r;
                }
            }
        }
    }
}

// ---------------- windowed attention: per (window, head) ----------------
__global__ __launch_bounds__(256) void attn_kernel(
    const ushort* __restrict__ qkv, const float* __restrict__ rpb,
    ushort* __restrict__ out, int win_off)
{
    __shared__ float Qs[49 * 33];
    __shared__ float Ks[49 * 33];
    __shared__ float Vs[49 * 33];
    __shared__ float S[49 * 50];

    const int widx = blockIdx.x;                 // chunk-local window index
    const int head = blockIdx.y;
    const int tid  = threadIdx.x;
    const size_t base = (size_t)widx * 49 * QKV_N + head * HDIM;

    for (int i = tid; i < 49 * 32; i += 256) {
        int tok = i >> 5, d = i & 31;
        size_t p = base + (size_t)tok * QKV_N + d;
        Qs[tok * 33 + d] = b2f(qkv[p]) * 0.17677669529663687f;  // 1/sqrt(32)
        Ks[tok * 33 + d] = b2f(qkv[p + 384]);
        Vs[tok * 33 + d] = b2f(qkv[p + 768]);
    }
    __syncthreads();

    const int w_ = (win_off + widx) & 63;        // window position in 8x8 grid
    const int wh = w_ >> 3, ww = w_ & 7;
    for (int idx = tid; idx < 49 * 49; idx += 256) {
        int i = idx / 49, j = idx - i * 49;
        float dot = 0.f;
        #pragma unroll
        for (int d = 0; d < 32; ++d) dot += Qs[i * 33 + d] * Ks[j * 33 + d];
        int ri = i / 7, ci = i - ri * 7;
        int rj = j / 7, cj = j - rj * 7;
        dot += rpb[((ri - rj + 6) * 13 + (ci - cj + 6)) * HEADS + head];
        int hi = wh * 7 + ri, hj = wh * 7 + rj;
        int wi = ww * 7 + ci, wj = ww * 7 + cj;
        int regi = (hi < 49 ? 0 : (hi < 53 ? 1 : 2)) * 3 + (wi < 49 ? 0 : (wi < 53 ? 1 : 2));
        int regj = (hj < 49 ? 0 : (hj < 53 ? 1 : 2)) * 3 + (wj < 49 ? 0 : (wj < 53 ? 1 : 2));
        if (regi != regj) dot -= 100.f;
        S[i * 50 + j] = dot;
    }
    __syncthreads();

    if (tid < 49) {
        const int i = tid;
        float mx = -1e30f;
        for (int j = 0; j < 49; ++j) mx = fmaxf(mx, S[i * 50 + j]);
        float sum = 0.f;
        for (int j = 0; j < 49; ++j) {
            float e = expf(S[i * 50 + j] - mx);
            S[i * 50 + j] = e; sum += e;
        }
        float inv = 1.f / sum;
        for (int j = 0; j < 49; ++j) S[i * 50 + j] *= inv;
    }
    __syncthreads();

    for (int idx = tid; idx < 49 * 32; idx += 256) {
        int i = idx >> 5, d = idx & 31;
        float o = 0.f;
        #pragma unroll
        for (int j = 0; j < 49; ++j) o += S[i * 50 + j] * Vs[j * 33 + d];
        out[((size_t)(widx * 49 + i)) * C_DIM + head * HDIM + d] = f2b(o);
    }
}

// ---------------- launch ----------------
extern "C" void kernel_launch(void* const* d_in, const int* in_sizes, int n_in,
                              void* d_out, int out_size, void* d_ws, size_t ws_size,
                              hipStream_t stream)
{
    const void* x      = d_in[0];
    const void* n1g    = d_in[3];
    const void* n1b    = d_in[4];
    const void* qkv_w  = d_in[5];
    const void* qkv_b  = d_in[6];
    const void* rpb    = d_in[7];
    const void* proj_w = d_in[8];
    const void* proj_b = d_in[9];
    const void* n2g    = d_in[10];
    const void* n2b    = d_in[11];
    const void* fc1_w  = d_in[12];
    const void* fc1_b  = d_in[13];
    const void* fc2_w  = d_in[14];
    const void* fc2_b  = d_in[15];

    // ---- workspace layout (bytes) ----
    // 0: dtype flag | 256: params f32 (7020 floats) | 28416: weights bf16 | WSTATIC: ws0/ws1
    int*    flagp = (int*)d_ws;
    float*  prm   = (float*)((char*)d_ws + 256);
    ushort* wq    = (ushort*)((char*)d_ws + 28416);       // 1152*384
    ushort* wp    = wq + 442368;                          // 384*384
    ushort* w1m   = wp + 147456;                          // 1536*384
    ushort* w2m   = w1m + 589824;                         // 384*1536
    const size_t WSTATIC = 3567360;                       // 28416 + 2*1769472

    int nc = 64;
    const int opts[7] = {1, 2, 4, 8, 16, 32, 64};
    for (int i = 0; i < 7; ++i) {
        size_t need = WSTATIC + ((size_t)M_TOK / opts[i]) * 3840ull;
        if (need <= ws_size) { nc = opts[i]; break; }
    }
    const int wins_pc = TOT_WIN / nc;
    const int rows_pc = wins_pc * NTOK;
    const int gx      = (rows_pc + 127) / 128;

    ushort* ws0 = (ushort*)((char*)d_ws + WSTATIC);       // rows_pc*384 bf16
    ushort* ws1 = ws0 + (size_t)rows_pc * C_DIM;          // rows_pc*1536 bf16

    // ---- front-end: sniff dtype, build canonical buffers ----
    sniff_kernel<<<1, 256, 0, stream>>>((const ushort*)x, flagp);
    cvt_p_kernel<<<1, 256, 0, stream>>>(n1g, n1b, qkv_b, proj_b, n2g, n2b,
                                        fc1_b, fc2_b, rpb, prm, flagp);
    cvt_w_kernel<<<432, 256, 0, stream>>>(qkv_w,  wq,  442368, flagp);
    cvt_w_kernel<<<144, 256, 0, stream>>>(proj_w, wp,  147456, flagp);
    cvt_w_kernel<<<576, 256, 0, stream>>>(fc1_w,  w1m, 589824, flagp);
    cvt_w_kernel<<<576, 256, 0, stream>>>(fc2_w,  w2m, 589824, flagp);

    const float* b_qkv = prm + 768;
    const float* b_prj = prm + 1920;
    const float* b_fc1 = prm + 3072;
    const float* b_fc2 = prm + 4608;
    const float* rpb_c = prm + 4992;

    // ---- phase A: attention path, per window-chunk ----
    for (int c = 0; c < nc; ++c) {
        const int moff = c * rows_pc;
        ln_kernel<0><<<rows_pc / 4, 256, 0, stream>>>(x, prm + 0, prm + 384, ws0, flagp, moff);
        gemm_bt<0><<<dim3(gx, 9), 256, 0, stream>>>(
            ws0, wq, b_qkv, ws1, nullptr, nullptr, flagp, QKV_N, C_DIM, rows_pc, 0);
        attn_kernel<<<dim3(wins_pc, HEADS), 256, 0, stream>>>(
            ws1, rpb_c, ws0, c * wins_pc);
        gemm_bt<1><<<dim3(gx, 3), 256, 0, stream>>>(
            ws0, wp, b_prj, nullptr, d_out, x, flagp, C_DIM, C_DIM, rows_pc, moff);
    }

    // ---- phase B: MLP path, per row-chunk (d_out rows hold x2) ----
    for (int c = 0; c < nc; ++c) {
        const int moff = c * rows_pc;
        ln_kernel<1><<<rows_pc / 4, 256, 0, stream>>>(d_out, prm + 2304, prm + 2688, ws0, flagp, moff);
        gemm_bt<2><<<dim3(gx, 12), 256, 0, stream>>>(
            ws0, w1m, b_fc1, ws1, nullptr, nullptr, flagp, MLP_N, C_DIM, rows_pc, 0);
        gemm_bt<3><<<dim3(gx, 3), 256, 0, stream>>>(
            ws1, w2m, b_fc2, nullptr, d_out, d_out, flagp, C_DIM, MLP_N, rows_pc, moff);
    }
}

// Round 5
// 1164.592 us; speedup vs baseline: 1.2523x; 1.2523x over previous
//
#include <hip/hip_runtime.h>
#include <hip/hip_bf16.h>

// ---------------- constants (Swin block geometry) ----------------
#define C_DIM   384
#define HEADS   12
#define HDIM    32
#define NTOK    49
#define TOT_WIN 2048        // 32 images * 64 windows
#define M_TOK   100352      // TOT_WIN*49
#define QKV_N   1152
#define MLP_N   1536
#define SHIFT_V 3

typedef __bf16 bf16x8_t __attribute__((ext_vector_type(8)));
typedef float  f32x4_t  __attribute__((ext_vector_type(4)));

__device__ inline float b2f(ushort u) {
    union { unsigned u; float f; } p; p.u = ((unsigned)u) << 16; return p.f;
}
__device__ inline ushort f2b(float f) {
    union { float f; unsigned u; } p; p.f = f;
    unsigned r = p.u + 0x7FFF + ((p.u >> 16) & 1);
    return (ushort)(r >> 16);
}
// dtype-branched scalar load from a native input buffer
__device__ inline float ldin(const void* p, size_t i, int dt) {
    return dt ? b2f(((const ushort*)p)[i]) : ((const float*)p)[i];
}

__device__ inline void gload_lds16(const ushort* g, ushort* l) {
    __builtin_amdgcn_global_load_lds(
        (__attribute__((address_space(1))) void*)const_cast<ushort*>(g),
        (__attribute__((address_space(3))) void*)l, 16, 0, 0);
}

// windowed-token index (global) -> original token row (shift roll, +3 mod 56)
__device__ inline int win2tok(int grow) {
    int widx = grow / 49, tok = grow - widx * 49;
    int b = widx >> 6, w_ = widx & 63;
    int wh = w_ >> 3, ww = w_ & 7;
    int r = tok / 7, c = tok - r * 7;
    int h = wh * 7 + r + SHIFT_V; if (h >= 56) h -= 56;
    int wc = ww * 7 + c + SHIFT_V; if (wc >= 56) wc -= 56;
    return b * 3136 + h * 56 + wc;
}

// ---------------- dtype sniffer: even-index ushorts sane-bf16 test ----------------
__global__ void sniff_kernel(const ushort* x16, int* flag) {
    const int tid = threadIdx.x;
    int cnt = 0;
    for (int i = tid; i < 4096; i += 256) {
        ushort u = x16[2 * i];
        int e = (u >> 7) & 0xFF;
        if ((u & 0x7FFF) == 0 || (e >= 107 && e <= 147)) cnt++;
    }
    __shared__ int ss[256];
    ss[tid] = cnt; __syncthreads();
    for (int s = 128; s; s >>= 1) { if (tid < s) ss[tid] += ss[tid + s]; __syncthreads(); }
    if (tid == 0) *flag = (ss[0] >= 2048) ? 1 : 0;   // 1 = bf16 storage, 0 = f32 storage
}

// ---------------- weight convert: native -> canonical bf16 ----------------
__global__ void cvt_w_kernel(const void* src, ushort* dst, int n, const int* flagp) {
    const int dt = *flagp;
    for (int i = blockIdx.x * blockDim.x + threadIdx.x; i < n; i += gridDim.x * blockDim.x)
        dst[i] = dt ? ((const ushort*)src)[i] : f2b(((const float*)src)[i]);
}

// ---------------- small params -> canonical f32 (concatenated) ----------------
// floats: n1g 0 | n1b 384 | qkv_b 768 | proj_b 1920 | n2g 2304 | n2b 2688 |
//         fc1_b 3072 | fc2_b 4608 | rpb 4992..7020
__global__ void cvt_p_kernel(const void* n1g, const void* n1b, const void* qkvb,
                             const void* projb, const void* n2g, const void* n2b,
                             const void* fc1b, const void* fc2b, const void* rpb,
                             float* prm, const int* flagp) {
    const int dt = *flagp;
    for (int i = threadIdx.x; i < 7020; i += 256) {
        float v;
        if      (i < 384)  v = ldin(n1g,  i,        dt);
        else if (i < 768)  v = ldin(n1b,  i - 384,  dt);
        else if (i < 1920) v = ldin(qkvb, i - 768,  dt);
        else if (i < 2304) v = ldin(projb,i - 1920, dt);
        else if (i < 2688) v = ldin(n2g,  i - 2304, dt);
        else if (i < 3072) v = ldin(n2b,  i - 2688, dt);
        else if (i < 4608) v = ldin(fc1b, i - 3072, dt);
        else if (i < 4992) v = ldin(fc2b, i - 4608, dt);
        else               v = ldin(rpb,  i - 4992, dt);
        prm[i] = v;
    }
}

// ---------------- LayerNorm ----------------
template<int MODE>
__global__ __launch_bounds__(256) void ln_kernel(
    const void* __restrict__ x, const float* __restrict__ g,
    const float* __restrict__ b, ushort* __restrict__ out,
    const int* flagp, int moff)
{
    const int dt = *flagp;
    const int wid = threadIdx.x >> 6, lane = threadIdx.x & 63;
    const int m = blockIdx.x * 4 + wid;
    const int src = (MODE == 0) ? win2tok(moff + m) : (moff + m);

    float v[6]; float s = 0.f, sq = 0.f;
    #pragma unroll
    for (int k = 0; k < 6; ++k) {
        v[k] = ldin(x, (size_t)src * C_DIM + lane + 64 * k, dt);
        s += v[k]; sq += v[k] * v[k];
    }
    #pragma unroll
    for (int off = 32; off; off >>= 1) {
        s  += __shfl_xor(s,  off, 64);
        sq += __shfl_xor(sq, off, 64);
    }
    float mean = s * (1.f / 384.f);
    float var  = sq * (1.f / 384.f) - mean * mean;
    float rstd = rsqrtf(var + 1e-5f);
    #pragma unroll
    for (int k = 0; k < 6; ++k) {
        int col = lane + 64 * k;
        out[(size_t)m * C_DIM + col] =
            f2b((v[k] - mean) * rstd * g[col] + b[col]);
    }
}

// ---------------- GEMM (global_load_lds staging, m97 structure) ----------------
// MODE 0: QKV->bf16 | 1: PROJ scatter+resid (dtype out) | 2: FC1+GELU->bf16 | 3: FC2+resid
template<int MODE>
__global__ __launch_bounds__(256, 2) void gemm_bt(
    const ushort* __restrict__ A, const ushort* __restrict__ W,
    const float* __restrict__ bias, ushort* outb, void* outv,
    const void* resid, const int* flagp, int N, int K, int Mrows, int moff)
{
    __shared__ __align__(16) ushort As[128 * 32];
    __shared__ __align__(16) ushort Bs[128 * 32];

    const int dt   = *flagp;
    const int tid  = threadIdx.x;
    const int wid  = tid >> 6;
    const int lane = tid & 63;
    const int bm = blockIdx.x * 128;
    const int bn = blockIdx.y * 128;
    const int wm = (wid >> 1) * 64;
    const int wn = (wid & 1) * 64;
    const int lrow = lane & 15;
    const int lk   = (lane >> 4) << 3;

    const int c0    = wid * 2;
    const int srow0 = c0 * 16 + (lane >> 2);          // 0..127
    const int srow1 = srow0 + 16;
    const int skoff = (lane & 3) << 3;                // 0,8,16,24 ushorts

    const int ar0 = (bm + srow0 < Mrows) ? (bm + srow0) : (Mrows - 1);
    const int ar1 = (bm + srow1 < Mrows) ? (bm + srow1) : (Mrows - 1);

    f32x4_t acc[4][4];
    #pragma unroll
    for (int m = 0; m < 4; ++m)
        #pragma unroll
        for (int n = 0; n < 4; ++n) acc[m][n] = (f32x4_t){0.f, 0.f, 0.f, 0.f};

    const int nk = K >> 5;
    for (int kt = 0; kt < nk; ++kt) {
        const int k0 = kt << 5;
        gload_lds16(A + (size_t)ar0 * K + k0 + skoff,         As + (c0)     * 512);
        gload_lds16(A + (size_t)ar1 * K + k0 + skoff,         As + (c0 + 1) * 512);
        gload_lds16(W + (size_t)(bn + srow0) * K + k0 + skoff, Bs + (c0)     * 512);
        gload_lds16(W + (size_t)(bn + srow1) * K + k0 + skoff, Bs + (c0 + 1) * 512);
        __syncthreads();
        bf16x8_t af[4], bfr[4];
        #pragma unroll
        for (int m = 0; m < 4; ++m)
            af[m] = *(const bf16x8_t*)&As[(wm + m * 16 + lrow) * 32 + lk];
        #pragma unroll
        for (int n = 0; n < 4; ++n)
            bfr[n] = *(const bf16x8_t*)&Bs[(wn + n * 16 + lrow) * 32 + lk];
        #pragma unroll
        for (int m = 0; m < 4; ++m)
            #pragma unroll
            for (int n = 0; n < 4; ++n)
                acc[m][n] = __builtin_amdgcn_mfma_f32_16x16x32_bf16(
                    af[m], bfr[n], acc[m][n], 0, 0, 0);
        __syncthreads();
    }

    float biasf[4]; int coln[4];
    #pragma unroll
    for (int n = 0; n < 4; ++n) {
        coln[n] = bn + wn + n * 16 + lrow;
        biasf[n] = bias[coln[n]];
    }
    const int rbase = bm + wm + ((lane >> 4) << 2);
    #pragma unroll
    for (int m = 0; m < 4; ++m) {
        #pragma unroll
        for (int j = 0; j < 4; ++j) {
            int grow = rbase + m * 16 + j;
            if (grow >= Mrows) continue;
            #pragma unroll
            for (int n = 0; n < 4; ++n) {
                float v = acc[m][n][j] + biasf[n];
                if (MODE == 0) {
                    outb[(size_t)grow * N + coln[n]] = f2b(v);
                } else if (MODE == 2) {
                    v = 0.5f * v * (1.0f + erff(v * 0.70710678118654752f));
                    outb[(size_t)grow * N + coln[n]] = f2b(v);
                } else {
                    size_t orow = (MODE == 1) ? (size_t)win2tok(moff + grow)
                                              : (size_t)(moff + grow);
                    size_t oidx = orow * (size_t)N + coln[n];
                    float r = v + ldin(resid, oidx, dt);
                    if (dt) ((ushort*)outv)[oidx] = f2b(r);
                    else    ((float*) outv)[oidx] = r;
                }
            }
        }
    }
}

// ---------------- MFMA windowed attention: 1 block/window, wave = 3 heads ----------------
// S^T = mfma(K,Q): St[m][n][j] = S[kk=m*16+hi*4+j][q=n*16+lo]; softmax over kk;
// P -> XOR-swizzled per-wave LDS; O = mfma(P, V^T).  No cross-wave sharing, no barriers.
__global__ __launch_bounds__(256) void attn_kernel(
    const ushort* __restrict__ qkv, const float* __restrict__ rpb,
    ushort* __restrict__ out, int win_off)
{
    __shared__ __align__(16) ushort Pl[4][64 * 64];   // 8KB per wave
    __shared__ __align__(16) ushort Vtl[4][32 * 64];  // 4KB per wave

    const int tid = threadIdx.x, wid = tid >> 6, lane = tid & 63;
    const int lo = lane & 15, hi = lane >> 4;
    const int widx = blockIdx.x;
    const int w_ = (win_off + widx) & 63;
    const int wh = w_ >> 3, ww = w_ & 7;
    const bool edge = (wh == 7) || (ww == 7);

    char* P  = (char*)Pl[wid];
    char* Vw = (char*)Vtl[wid];

    // q-side geometry (St cols): q = n*16+lo
    int qr[4], qc[4], rq[4];
    #pragma unroll
    for (int n = 0; n < 4; ++n) {
        int q = n * 16 + lo; if (q > 48) q = 48;
        qr[n] = q / 7; qc[n] = q - qr[n] * 7;
        int gh = wh * 7 + qr[n], gw = ww * 7 + qc[n];
        rq[n] = (gh < 49 ? 0 : (gh < 53 ? 1 : 2)) * 3 + (gw < 49 ? 0 : (gw < 53 ? 1 : 2));
    }

    for (int h = wid; h < HEADS; h += 4) {
        const size_t hb = (size_t)widx * 49 * QKV_N + h * HDIM;

        // K rows as A-frags, Q rows as B-frags, direct from global (zero-pad rows>=49)
        bf16x8_t kf[4], qf[4];
        #pragma unroll
        for (int t = 0; t < 4; ++t) {
            int r = t * 16 + lo;
            bf16x8_t z = {};
            kf[t] = z; qf[t] = z;
            if (r < 49) {
                kf[t] = *(const bf16x8_t*)(qkv + hb + (size_t)r * QKV_N + 384 + hi * 8);
                qf[t] = *(const bf16x8_t*)(qkv + hb + (size_t)r * QKV_N + hi * 8);
            }
        }

        // stage V^T into swizzled LDS: lane = token kk, zero rows kk>=49
        {
            const int kk = lane;
            union { bf16x8_t v; ushort u[8]; } vv[4];
            #pragma unroll
            for (int c = 0; c < 4; ++c) {
                bf16x8_t z = {};
                vv[c].v = (kk < 49) ? *(const bf16x8_t*)(qkv + hb + (size_t)kk * QKV_N + 768 + c * 8)
                                    : z;
            }
            #pragma unroll
            for (int d = 0; d < 32; ++d) {
                int byo = (d * 128 + kk * 2) ^ ((d & 7) << 4);
                *(ushort*)(Vw + byo) = vv[d >> 3].u[d & 7];
            }
        }

        // S^T = K·Q^T (16 MFMAs)
        f32x4_t St[4][4];
        #pragma unroll
        for (int m = 0; m < 4; ++m)
            #pragma unroll
            for (int n = 0; n < 4; ++n) St[m][n] = (f32x4_t){0.f, 0.f, 0.f, 0.f};
        #pragma unroll
        for (int m = 0; m < 4; ++m)
            #pragma unroll
            for (int n = 0; n < 4; ++n)
                St[m][n] = __builtin_amdgcn_mfma_f32_16x16x32_bf16(kf[m], qf[n], St[m][n], 0, 0, 0);

        // scale + rel-pos bias + shift-mask + col(kk)-mask
        #pragma unroll
        for (int m = 0; m < 4; ++m) {
            #pragma unroll
            for (int j = 0; j < 4; ++j) {
                const int kk = m * 16 + hi * 4 + j;
                const int kcl = (kk > 48) ? 48 : kk;
                const int kr = kcl / 7, kc = kcl - kr * 7;
                int rk = 0;
                if (edge) {
                    int gh = wh * 7 + kr, gw = ww * 7 + kc;
                    rk = (gh < 49 ? 0 : (gh < 53 ? 1 : 2)) * 3 + (gw < 49 ? 0 : (gw < 53 ? 1 : 2));
                }
                #pragma unroll
                for (int n = 0; n < 4; ++n) {
                    int idx = (qr[n] - kr + 6) * 13 + (qc[n] - kc + 6);
                    float v = St[m][n][j] * 0.17677669529663687f + rpb[idx * 12 + h];
                    if (edge && (rq[n] != rk)) v -= 100.f;
                    if (kk > 48) v = -1e30f;
                    St[m][n][j] = v;
                }
            }
        }

        // softmax over kk per q-column (local m,j then hi-groups via shfl_xor 16/32)
        float mx[4], sm[4];
        #pragma unroll
        for (int n = 0; n < 4; ++n) {
            float mv = St[0][n][0];
            #pragma unroll
            for (int m = 0; m < 4; ++m)
                #pragma unroll
                for (int j = 0; j < 4; ++j) mv = fmaxf(mv, St[m][n][j]);
            mv = fmaxf(mv, __shfl_xor(mv, 16, 64));
            mv = fmaxf(mv, __shfl_xor(mv, 32, 64));
            mx[n] = mv;
            float sv = 0.f;
            #pragma unroll
            for (int m = 0; m < 4; ++m)
                #pragma unroll
                for (int j = 0; j < 4; ++j) {
                    float e = __expf(St[m][n][j] - mv);
                    St[m][n][j] = e; sv += e;
                }
            sv += __shfl_xor(sv, 16, 64);
            sv += __shfl_xor(sv, 32, 64);
            sm[n] = 1.f / sv;
        }

        // P = St * inv  -> bf16 -> swizzled LDS  (row q, col kk; 8B packed writes)
        #pragma unroll
        for (int m = 0; m < 4; ++m) {
            #pragma unroll
            for (int n = 0; n < 4; ++n) {
                union { ushort4 u4; __bf16 b[4]; } pk;
                #pragma unroll
                for (int j = 0; j < 4; ++j) pk.b[j] = (__bf16)(St[m][n][j] * sm[n]);
                int byo = ((n * 16 + lo) * 128 + (m * 16 + hi * 4) * 2) ^ ((lo & 7) << 4);
                *(ushort4*)(P + byo) = pk.u4;
            }
        }

        // O = P · V  (A = P rows q, B = Vt rows d; K=64 in 2 steps)
        f32x4_t Oa[4][2];
        #pragma unroll
        for (int mt = 0; mt < 4; ++mt)
            #pragma unroll
            for (int nt = 0; nt < 2; ++nt) Oa[mt][nt] = (f32x4_t){0.f, 0.f, 0.f, 0.f};
        #pragma unroll
        for (int s = 0; s < 2; ++s) {
            bf16x8_t vf[2];
            #pragma unroll
            for (int nt = 0; nt < 2; ++nt) {
                int byo = ((nt * 16 + lo) * 128 + s * 64 + hi * 16) ^ ((lo & 7) << 4);
                vf[nt] = *(const bf16x8_t*)(Vw + byo);
            }
            #pragma unroll
            for (int mt = 0; mt < 4; ++mt) {
                int byo = ((mt * 16 + lo) * 128 + s * 64 + hi * 16) ^ ((lo & 7) << 4);
                bf16x8_t pf = *(const bf16x8_t*)(P + byo);
                #pragma unroll
                for (int nt = 0; nt < 2; ++nt)
                    Oa[mt][nt] = __builtin_amdgcn_mfma_f32_16x16x32_bf16(pf, vf[nt], Oa[mt][nt], 0, 0, 0);
            }
        }

        // store O rows < 49
        #pragma unroll
        for (int mt = 0; mt < 4; ++mt) {
            #pragma unroll
            for (int j = 0; j < 4; ++j) {
                int q = mt * 16 + hi * 4 + j;
                if (q < 49) {
                    size_t ro = ((size_t)(widx * 49 + q)) * C_DIM + h * HDIM;
                    #pragma unroll
                    for (int nt = 0; nt < 2; ++nt)
                        out[ro + nt * 16 + lo] = f2b(Oa[mt][nt][j]);
                }
            }
        }
    }
}

// ---------------- launch ----------------
extern "C" void kernel_launch(void* const* d_in, const int* in_sizes, int n_in,
                              void* d_out, int out_size, void* d_ws, size_t ws_size,
                              hipStream_t stream)
{
    const void* x      = d_in[0];
    const void* n1g    = d_in[3];
    const void* n1b    = d_in[4];
    const void* qkv_w  = d_in[5];
    const void* qkv_b  = d_in[6];
    const void* rpb    = d_in[7];
    const void* proj_w = d_in[8];
    const void* proj_b = d_in[9];
    const void* n2g    = d_in[10];
    const void* n2b    = d_in[11];
    const void* fc1_w  = d_in[12];
    const void* fc1_b  = d_in[13];
    const void* fc2_w  = d_in[14];
    const void* fc2_b  = d_in[15];

    // ws: 0 flag | 256 prm f32 | 28416 weights bf16 | WSTATIC ws0/ws1
    int*    flagp = (int*)d_ws;
    float*  prm   = (float*)((char*)d_ws + 256);
    ushort* wq    = (ushort*)((char*)d_ws + 28416);
    ushort* wp    = wq + 442368;
    ushort* w1m   = wp + 147456;
    ushort* w2m   = w1m + 589824;
    const size_t WSTATIC = 3567360;

    int nc = 64;
    const int opts[7] = {1, 2, 4, 8, 16, 32, 64};
    for (int i = 0; i < 7; ++i) {
        size_t need = WSTATIC + ((size_t)M_TOK / opts[i]) * 3840ull;
        if (need <= ws_size) { nc = opts[i]; break; }
    }
    const int wins_pc = TOT_WIN / nc;
    const int rows_pc = wins_pc * NTOK;
    const int gx      = (rows_pc + 127) / 128;

    ushort* ws0 = (ushort*)((char*)d_ws + WSTATIC);
    ushort* ws1 = ws0 + (size_t)rows_pc * C_DIM;

    sniff_kernel<<<1, 256, 0, stream>>>((const ushort*)x, flagp);
    cvt_p_kernel<<<1, 256, 0, stream>>>(n1g, n1b, qkv_b, proj_b, n2g, n2b,
                                        fc1_b, fc2_b, rpb, prm, flagp);
    cvt_w_kernel<<<432, 256, 0, stream>>>(qkv_w,  wq,  442368, flagp);
    cvt_w_kernel<<<144, 256, 0, stream>>>(proj_w, wp,  147456, flagp);
    cvt_w_kernel<<<576, 256, 0, stream>>>(fc1_w,  w1m, 589824, flagp);
    cvt_w_kernel<<<576, 256, 0, stream>>>(fc2_w,  w2m, 589824, flagp);

    const float* b_qkv = prm + 768;
    const float* b_prj = prm + 1920;
    const float* b_fc1 = prm + 3072;
    const float* b_fc2 = prm + 4608;
    const float* rpb_c = prm + 4992;

    for (int c = 0; c < nc; ++c) {
        const int moff = c * rows_pc;
        ln_kernel<0><<<rows_pc / 4, 256, 0, stream>>>(x, prm + 0, prm + 384, ws0, flagp, moff);
        gemm_bt<0><<<dim3(gx, 9), 256, 0, stream>>>(
            ws0, wq, b_qkv, ws1, nullptr, nullptr, flagp, QKV_N, C_DIM, rows_pc, 0);
        attn_kernel<<<wins_pc, 256, 0, stream>>>(ws1, rpb_c, ws0, c * wins_pc);
        gemm_bt<1><<<dim3(gx, 3), 256, 0, stream>>>(
            ws0, wp, b_prj, nullptr, d_out, x, flagp, C_DIM, C_DIM, rows_pc, moff);
    }

    for (int c = 0; c < nc; ++c) {
        const int moff = c * rows_pc;
        ln_kernel<1><<<rows_pc / 4, 256, 0, stream>>>(d_out, prm + 2304, prm + 2688, ws0, flagp, moff);
        gemm_bt<2><<<dim3(gx, 12), 256, 0, stream>>>(
            ws0, w1m, b_fc1, ws1, nullptr, nullptr, flagp, MLP_N, C_DIM, rows_pc, 0);
        gemm_bt<3><<<dim3(gx, 3), 256, 0, stream>>>(
            ws1, w2m, b_fc2, nullptr, d_out, d_out, flagp, C_DIM, MLP_N, rows_pc, moff);
    }
}